// Round 8
// baseline (35.002 us; speedup 1.0000x reference)
//
#include <hip/hip_runtime.h>

#define IH 224
#define IW 224
#define PH 55
#define PW 55
#define CH_CELLS (56 * 64)        // stage-1 cells (row-group x col-chunk) per channel
#define ALL_CELLS (3 * CH_CELLS)  // 10752
#define P_CELLS (55 * 64)         // stage-2 cells per channel
#define ALL_P (3 * P_CELLS)       // 10560

typedef float fx4 __attribute__((ext_vector_type(4)));

__device__ __forceinline__ fx4 max4(fx4 a, fx4 b) {
  fx4 r;
  r.x = fmaxf(a.x, b.x); r.y = fmaxf(a.y, b.y);
  r.z = fmaxf(a.z, b.z); r.w = fmaxf(a.w, b.w);
  return r;
}

__device__ __forceinline__ float cell_max_nt(const float* __restrict__ p0) {
  // 4 contiguous rows x 4-col chunk: four 16B non-temporal loads
  fx4 a0 = __builtin_nontemporal_load(reinterpret_cast<const fx4*>(p0));
  fx4 a1 = __builtin_nontemporal_load(reinterpret_cast<const fx4*>(p0 + IW));
  fx4 a2 = __builtin_nontemporal_load(reinterpret_cast<const fx4*>(p0 + 2 * IW));
  fx4 a3 = __builtin_nontemporal_load(reinterpret_cast<const fx4*>(p0 + 3 * IW));
  fx4 mm = max4(max4(a0, a1), max4(a2, a3));
  return fmaxf(fmaxf(mm.x, mm.y), fmaxf(mm.z, mm.w));
}

// One block per batch, fully fused, single dispatch.  Stage-1 streaming loop
// manually unrolled 2x: 8 independent float4 loads in flight per wave
// (vs 4), non-temporal reads.
__global__ __launch_bounds__(1024, 4) void fused_kernel(
    const float* __restrict__ x,
    const int* __restrict__ R,
    float* __restrict__ out)
{
  __shared__ float gm[ALL_CELLS];   // 43 KB
  __shared__ int   sR[512];
  __shared__ float rmin[16], rmax[16];
  __shared__ float sMin, sMax;

  const int b = blockIdx.x;
  const int t = threadIdx.x;
  const float NEG = -3.4e38f;

  if (t < 512) sR[t] = R[t];

  // zero this batch's output row (2048 float4, 2 per thread) — overlaps reads
  {
    fx4* orow4 = reinterpret_cast<fx4*>(out + (size_t)b * 8192);
    const fx4 z = (fx4)(0.f);
    orow4[t] = z;
    orow4[t + 1024] = z;
  }

  const float* img = x + (size_t)b * (3 * IH * IW);

  // stage 1: gm[c][g][wp] = max over rows 4g..4g+3, cols 4wp..4wp+7
  int i = t;
  for (; i + 1024 < ALL_CELLS; i += 2048) {
    const int i1 = i + 1024;
    const int c0 = i  / CH_CELLS, r0 = i  - c0 * CH_CELLS;
    const int c1 = i1 / CH_CELLS, r1 = i1 - c1 * CH_CELLS;
    const int g0 = r0 >> 6, wp0 = r0 & 63;
    const int g1 = r1 >> 6, wp1 = r1 & 63;
    float cm0 = NEG, cm1 = NEG;
    if (wp0 < 56) cm0 = cell_max_nt(img + c0 * (IH * IW) + (4 * g0) * IW + 4 * wp0);
    if (wp1 < 56) cm1 = cell_max_nt(img + c1 * (IH * IW) + (4 * g1) * IW + 4 * wp1);
    const float nb0 = __shfl_down(cm0, 1);
    const float nb1 = __shfl_down(cm1, 1);
    gm[i]  = fmaxf(cm0, nb0);
    gm[i1] = fmaxf(cm1, nb1);
  }
  if (i < ALL_CELLS) {
    const int c0 = i / CH_CELLS, r0 = i - c0 * CH_CELLS;
    const int g0 = r0 >> 6, wp0 = r0 & 63;
    float cm0 = NEG;
    if (wp0 < 56) cm0 = cell_max_nt(img + c0 * (IH * IW) + (4 * g0) * IW + 4 * wp0);
    const float nb0 = __shfl_down(cm0, 1);
    gm[i] = fmaxf(cm0, nb0);
  }
  __syncthreads();

  // stage 2: pooled[c][hp][w] = max(gm[c][hp], gm[c][hp+1]); reduce min/max
  float lmin = 3.4e38f, lmax = NEG;
  for (int q = t; q < ALL_P; q += 1024) {
    const int c = q / P_CELLS;
    const int r = q - c * P_CELLS;
    const int w = r & 63;
    if (w < PW) {
      float pm = fmaxf(gm[c * CH_CELLS + r], gm[c * CH_CELLS + r + 64]);
      lmin = fminf(lmin, pm);
      lmax = fmaxf(lmax, pm);
    }
  }
  for (int off = 32; off > 0; off >>= 1) {
    lmin = fminf(lmin, __shfl_down(lmin, off));
    lmax = fmaxf(lmax, __shfl_down(lmax, off));
  }
  if ((t & 63) == 0) { rmin[t >> 6] = lmin; rmax[t >> 6] = lmax; }
  __syncthreads();
  if (t == 0) {
    float mn = rmin[0], mx = rmax[0];
    #pragma unroll
    for (int k = 1; k < 16; ++k) {
      mn = fminf(mn, rmin[k]);
      mx = fmaxf(mx, rmax[k]);
    }
    sMin = mn; sMax = mx;
  }
  __syncthreads();

  // encode: 64 hash positions, one 1.0 store each
  if (t < 64) {
    const float xmin  = sMin;
    const float denom = sMax - xmin + 1e-8f;   // same op order as reference
    int p = 0;
    #pragma unroll
    for (int k = 0; k < 8; ++k) {
      int idx = sR[t * 8 + k] % 72600;   // n_elements = 3*55*55*8
      int f   = idx >> 3;
      int l   = idx & 7;
      int c   = f / 3025;
      int rem = f - c * 3025;
      int hp  = rem / 55;
      int w   = rem - hp * 55;
      float pm = fmaxf(gm[c * CH_CELLS + hp * 64 + w],
                       gm[c * CH_CELLS + hp * 64 + 64 + w]);
      float xn = (pm - xmin) / denom;
      if (xn > (float)(l + 1) * 0.125f) p += 128 >> k;
    }
    out[(size_t)b * 8192 + t * 128 + (p & 127)] = 1.0f;
  }
}

extern "C" void kernel_launch(void* const* d_in, const int* in_sizes, int n_in,
                              void* d_out, int out_size, void* d_ws, size_t ws_size,
                              hipStream_t stream) {
  const float* x   = (const float*)d_in[0];
  const int*   R   = (const int*)d_in[1];
  float*       out = (float*)d_out;

  fused_kernel<<<256, 1024, 0, stream>>>(x, R, out);
}

// Round 9
// 32.823 us; speedup vs baseline: 1.0664x; 1.0664x over previous
//
#include <hip/hip_runtime.h>

#define IH 224
#define IW 224
#define CHW (IH * IW)          // 50176 floats per channel
#define NCH_CELLS (56 * 56)    // 3136 4x4-row-col chunks per channel
#define NCELLS (3 * NCH_CELLS) // 9408
#define NP_CELLS (55 * 55)     // 3025 pooled cells per channel
#define NP_ALL (3 * NP_CELLS)  // 9075

typedef float fx4 __attribute__((ext_vector_type(4)));

__device__ __forceinline__ fx4 max4(fx4 a, fx4 b) {
  fx4 r;
  r.x = fmaxf(a.x, b.x); r.y = fmaxf(a.y, b.y);
  r.z = fmaxf(a.z, b.z); r.w = fmaxf(a.w, b.w);
  return r;
}

// One block per batch, single dispatch. Stage 1: flat cell mapping — all 64
// lanes of every wave issue loads every iteration (no idle lanes, no
// predication). Each cell = 4 rows x 4 cols chunk max -> LDS. Stage 2 folds
// the 2x2-chunk window combine (window 8 = 2 chunks/axis) + min/max reduce.
__global__ __launch_bounds__(1024, 4) void fused_kernel(
    const float* __restrict__ x,
    const int* __restrict__ R,
    float* __restrict__ out)
{
  __shared__ float gmr[NCELLS];   // 37.6 KB: per-chunk maxes
  __shared__ int   sR[512];
  __shared__ float rmin[16], rmax[16];
  __shared__ float sMin, sMax;

  const int b = blockIdx.x;
  const int t = threadIdx.x;
  const float NEG = -3.4e38f;

  if (t < 512) sR[t] = R[t];

  // zero this batch's output row (2048 fx4, 2 per thread) — overlaps reads
  {
    fx4* orow4 = reinterpret_cast<fx4*>(out + (size_t)b * 8192);
    const fx4 z = (fx4)(0.f);
    orow4[t] = z;
    orow4[t + 1024] = z;
  }

  const float* img = x + (size_t)b * (3 * CHW);

  // stage 1: gmr[c][g][wp] = max over rows 4g..4g+3, cols 4wp..4wp+3
  for (int j = t; j < NCELLS; j += 1024) {
    const int c  = j / NCH_CELLS;
    const int r  = j - c * NCH_CELLS;
    const int g  = r / 56;
    const int wp = r - g * 56;
    const float* p0 = img + c * CHW + (4 * g) * IW + 4 * wp;
    fx4 a0 = *reinterpret_cast<const fx4*>(p0);
    fx4 a1 = *reinterpret_cast<const fx4*>(p0 + IW);
    fx4 a2 = *reinterpret_cast<const fx4*>(p0 + 2 * IW);
    fx4 a3 = *reinterpret_cast<const fx4*>(p0 + 3 * IW);
    fx4 mm = max4(max4(a0, a1), max4(a2, a3));
    gmr[j] = fmaxf(fmaxf(mm.x, mm.y), fmaxf(mm.z, mm.w));
  }
  __syncthreads();

  // stage 2: pooled[c][hp][w] = max of 2x2 chunk block; reduce min/max
  float lmin = 3.4e38f, lmax = NEG;
  for (int q = t; q < NP_ALL; q += 1024) {
    const int c  = q / NP_CELLS;
    const int r  = q - c * NP_CELLS;
    const int hp = r / 55;
    const int w  = r - hp * 55;
    const float* gp = gmr + c * NCH_CELLS + hp * 56 + w;
    float pm = fmaxf(fmaxf(gp[0], gp[1]), fmaxf(gp[56], gp[57]));
    lmin = fminf(lmin, pm);
    lmax = fmaxf(lmax, pm);
  }
  for (int off = 32; off > 0; off >>= 1) {
    lmin = fminf(lmin, __shfl_down(lmin, off));
    lmax = fmaxf(lmax, __shfl_down(lmax, off));
  }
  if ((t & 63) == 0) { rmin[t >> 6] = lmin; rmax[t >> 6] = lmax; }
  __syncthreads();
  if (t == 0) {
    float mn = rmin[0], mx = rmax[0];
    #pragma unroll
    for (int k = 1; k < 16; ++k) {
      mn = fminf(mn, rmin[k]);
      mx = fmaxf(mx, rmax[k]);
    }
    sMin = mn; sMax = mx;
  }
  __syncthreads();

  // encode: 64 hash positions, one 1.0 store each
  if (t < 64) {
    const float xmin  = sMin;
    const float denom = sMax - xmin + 1e-8f;   // same op order as reference
    int p = 0;
    #pragma unroll
    for (int k = 0; k < 8; ++k) {
      int idx = sR[t * 8 + k] % 72600;   // n_elements = 3*55*55*8
      int f   = idx >> 3;
      int l   = idx & 7;
      int c   = f / NP_CELLS;
      int rem = f - c * NP_CELLS;
      int hp  = rem / 55;
      int w   = rem - hp * 55;
      const float* gp = gmr + c * NCH_CELLS + hp * 56 + w;
      float pm = fmaxf(fmaxf(gp[0], gp[1]), fmaxf(gp[56], gp[57]));
      float xn = (pm - xmin) / denom;
      if (xn > (float)(l + 1) * 0.125f) p += 128 >> k;
    }
    out[(size_t)b * 8192 + t * 128 + (p & 127)] = 1.0f;
  }
}

extern "C" void kernel_launch(void* const* d_in, const int* in_sizes, int n_in,
                              void* d_out, int out_size, void* d_ws, size_t ws_size,
                              hipStream_t stream) {
  const float* x   = (const float*)d_in[0];
  const int*   R   = (const int*)d_in[1];
  float*       out = (float*)d_out;

  fused_kernel<<<256, 1024, 0, stream>>>(x, R, out);
}

// Round 10
// 30.931 us; speedup vs baseline: 1.1316x; 1.0612x over previous
//
#include <hip/hip_runtime.h>

#define IH 224
#define IW 224
#define CHW (IH * IW)          // 50176 floats per channel
#define NCH_CELLS (56 * 56)    // 3136 4x4 chunks per channel
#define NCELLS (3 * NCH_CELLS) // 9408
#define NP_CELLS (55 * 55)     // 3025 pooled cells per channel
#define NP_ALL (3 * NP_CELLS)  // 9075

typedef float fx4 __attribute__((ext_vector_type(4)));

__device__ __forceinline__ fx4 max4(fx4 a, fx4 b) {
  fx4 r;
  r.x = fmaxf(a.x, b.x); r.y = fmaxf(a.y, b.y);
  r.z = fmaxf(a.z, b.z); r.w = fmaxf(a.w, b.w);
  return r;
}

// chunk max: 4 rows x 4 cols, four 16B loads
__device__ __forceinline__ float cell_max(const float* __restrict__ p0) {
  fx4 a0 = *reinterpret_cast<const fx4*>(p0);
  fx4 a1 = *reinterpret_cast<const fx4*>(p0 + IW);
  fx4 a2 = *reinterpret_cast<const fx4*>(p0 + 2 * IW);
  fx4 a3 = *reinterpret_cast<const fx4*>(p0 + 3 * IW);
  fx4 mm = max4(max4(a0, a1), max4(a2, a3));
  return fmaxf(fmaxf(mm.x, mm.y), fmaxf(mm.z, mm.w));
}

__device__ __forceinline__ const float* cell_addr(const float* __restrict__ img, int j) {
  const int c  = j / NCH_CELLS;
  const int r  = j - c * NCH_CELLS;
  const int g  = r / 56;
  const int wp = r - g * 56;
  return img + c * CHW + (4 * g) * IW + 4 * wp;
}

// One block per batch, single dispatch. Stage 1: pure-read streaming (output
// zeroing deferred to the tail), flat cell mapping, 2x unroll = 8 independent
// 16B loads in flight per wave.
__global__ __launch_bounds__(1024, 4) void fused_kernel(
    const float* __restrict__ x,
    const int* __restrict__ R,
    float* __restrict__ out)
{
  __shared__ float gmr[NCELLS];   // 37.6 KB: per-chunk maxes
  __shared__ int   sR[512];
  __shared__ float rmin[16], rmax[16];
  __shared__ float sMin, sMax;

  const int b = blockIdx.x;
  const int t = threadIdx.x;
  const float NEG = -3.4e38f;

  if (t < 512) sR[t] = R[t];

  const float* img = x + (size_t)b * (3 * CHW);

  // stage 1: gmr[c][g][wp] = max over rows 4g..4g+3, cols 4wp..4wp+3
  int j = t;
  for (; j + 1024 < NCELLS; j += 2048) {
    const float* pa = cell_addr(img, j);
    const float* pb = cell_addr(img, j + 1024);
    // issue both cells' loads before reducing (8 loads in flight)
    fx4 a0 = *reinterpret_cast<const fx4*>(pa);
    fx4 a1 = *reinterpret_cast<const fx4*>(pa + IW);
    fx4 a2 = *reinterpret_cast<const fx4*>(pa + 2 * IW);
    fx4 a3 = *reinterpret_cast<const fx4*>(pa + 3 * IW);
    fx4 b0 = *reinterpret_cast<const fx4*>(pb);
    fx4 b1 = *reinterpret_cast<const fx4*>(pb + IW);
    fx4 b2 = *reinterpret_cast<const fx4*>(pb + 2 * IW);
    fx4 b3 = *reinterpret_cast<const fx4*>(pb + 3 * IW);
    fx4 ma = max4(max4(a0, a1), max4(a2, a3));
    fx4 mb = max4(max4(b0, b1), max4(b2, b3));
    gmr[j]        = fmaxf(fmaxf(ma.x, ma.y), fmaxf(ma.z, ma.w));
    gmr[j + 1024] = fmaxf(fmaxf(mb.x, mb.y), fmaxf(mb.z, mb.w));
  }
  for (; j < NCELLS; j += 1024) {
    gmr[j] = cell_max(cell_addr(img, j));
  }
  __syncthreads();

  // stage 2: pooled[c][hp][w] = max of 2x2 chunk block; reduce min/max
  float lmin = 3.4e38f, lmax = NEG;
  for (int q = t; q < NP_ALL; q += 1024) {
    const int c  = q / NP_CELLS;
    const int r  = q - c * NP_CELLS;
    const int hp = r / 55;
    const int w  = r - hp * 55;
    const float* gp = gmr + c * NCH_CELLS + hp * 56 + w;
    float pm = fmaxf(fmaxf(gp[0], gp[1]), fmaxf(gp[56], gp[57]));
    lmin = fminf(lmin, pm);
    lmax = fmaxf(lmax, pm);
  }
  for (int off = 32; off > 0; off >>= 1) {
    lmin = fminf(lmin, __shfl_down(lmin, off));
    lmax = fmaxf(lmax, __shfl_down(lmax, off));
  }
  if ((t & 63) == 0) { rmin[t >> 6] = lmin; rmax[t >> 6] = lmax; }

  // zero this batch's output row NOW (write burst after the read stream)
  {
    fx4* orow4 = reinterpret_cast<fx4*>(out + (size_t)b * 8192);
    const fx4 z = (fx4)(0.f);
    orow4[t] = z;
    orow4[t + 1024] = z;
  }
  __syncthreads();   // publishes rmin/rmax AND drains the zero-stores

  if (t == 0) {
    float mn = rmin[0], mx = rmax[0];
    #pragma unroll
    for (int k = 1; k < 16; ++k) {
      mn = fminf(mn, rmin[k]);
      mx = fmaxf(mx, rmax[k]);
    }
    sMin = mn; sMax = mx;
  }
  __syncthreads();

  // encode: 64 hash positions, one 1.0 store each
  if (t < 64) {
    const float xmin  = sMin;
    const float denom = sMax - xmin + 1e-8f;   // same op order as reference
    int p = 0;
    #pragma unroll
    for (int k = 0; k < 8; ++k) {
      int idx = sR[t * 8 + k] % 72600;   // n_elements = 3*55*55*8
      int f   = idx >> 3;
      int l   = idx & 7;
      int c   = f / NP_CELLS;
      int rem = f - c * NP_CELLS;
      int hp  = rem / 55;
      int w   = rem - hp * 55;
      const float* gp = gmr + c * NCH_CELLS + hp * 56 + w;
      float pm = fmaxf(fmaxf(gp[0], gp[1]), fmaxf(gp[56], gp[57]));
      float xn = (pm - xmin) / denom;
      if (xn > (float)(l + 1) * 0.125f) p += 128 >> k;
    }
    out[(size_t)b * 8192 + t * 128 + (p & 127)] = 1.0f;
  }
}

extern "C" void kernel_launch(void* const* d_in, const int* in_sizes, int n_in,
                              void* d_out, int out_size, void* d_ws, size_t ws_size,
                              hipStream_t stream) {
  const float* x   = (const float*)d_in[0];
  const int*   R   = (const int*)d_in[1];
  float*       out = (float*)d_out;

  fused_kernel<<<256, 1024, 0, stream>>>(x, R, out);
}